// Round 5
// baseline (497.050 us; speedup 1.0000x reference)
//
#include <hip/hip_runtime.h>

#define TT 512

typedef __attribute__((ext_vector_type(8))) short bf16x8;
typedef __attribute__((ext_vector_type(4))) short s16x4;
typedef __attribute__((ext_vector_type(4))) float f32x4;

__device__ inline short f2bf(float f) {
    // round-to-nearest-even fp32 -> bf16 (values bounded; no NaN path needed)
    unsigned u = __float_as_uint(f);
    u += 0x7FFFu + ((u >> 16) & 1u);
    return (short)(u >> 16);
}

// quad-broadcast: every lane gets quad-lane-0's 16B granule (VALU DPP, no LDS)
__device__ inline bf16x8 qbcast(int4 t) {
    int4 r;
    r.x = __builtin_amdgcn_mov_dpp(t.x, 0, 0xF, 0xF, true);
    r.y = __builtin_amdgcn_mov_dpp(t.y, 0, 0xF, 0xF, true);
    r.z = __builtin_amdgcn_mov_dpp(t.z, 0, 0xF, 0xF, true);
    r.w = __builtin_amdgcn_mov_dpp(t.w, 0, 0xF, 0xF, true);
    union { int4 i; bf16x8 b; } u_; u_.i = r; return u_.b;
}

#define MFMA16(a, b, c) __builtin_amdgcn_mfma_f32_16x16x32_bf16((a), (b), (c), 0, 0, 0)

// 768 threads = 12 waves = 3 layers x 4 unit-quarters (16 units each).
// WG owns 4 batch rows for all T; grid = 256 = 1 WG/CU. Barrier per step
// (R4 showed flag-sync is slower than s_barrier rendezvous).
// A-frag rows replicated 4x (A row r = batch row r>>2): lanes in each quad
// need the SAME 16B LDS granule -> only lanes l&3==0 issue ds_read_b128,
// others get it via v_mov_dpp quad_perm broadcast. 4x less LDS read traffic
// (the shared LDS return path was the hidden per-step serializer).
// i-part and h-part accumulate in separate depth-2 MFMA chains, joined by
// a scalar add. Gate transcendentals use exp2 directly: r/z weights+biases
// pre-scaled by -log2e, n-gate by 2*log2e at frag build.
__global__ __launch_bounds__(768, 1)
void gru_fused(const float* __restrict__ x,
               const float* __restrict__ Wih0, const float* __restrict__ Whh0,
               const float* __restrict__ bih0, const float* __restrict__ bhh0,
               const float* __restrict__ Wih1, const float* __restrict__ Whh1,
               const float* __restrict__ bih1, const float* __restrict__ bhh1,
               const float* __restrict__ Wih2, const float* __restrict__ Whh2,
               const float* __restrict__ bih2, const float* __restrict__ bhh2,
               const float* __restrict__ fc1w, const float* __restrict__ fc1b,
               const float* __restrict__ fc2w, const float* __restrict__ fc2b,
               float* __restrict__ out)
{
    // x as bf16: [t][row][16], unpadded (64 KiB). Layer-0 A-frags exec-masked q<2.
    __shared__ __align__(16) short xls[TT][4][16];
    // h double buffers: row stride 80 shorts (16B-aligned granules, 2-way banks).
    __shared__ __align__(16) short hbuf[3][2][4 * 80];
    __shared__ float h2out[4][64];
    __shared__ float fcz[4][32];

    const int tid = threadIdx.x;
    const int l   = tid & 63;
    const int wid = tid >> 6;                       // 0..11
    const int Ls  = __builtin_amdgcn_readfirstlane(wid >> 2);  // layer 0..2 (scalar)
    const int qt  = wid & 3;                        // unit quarter
    const int n_  = l & 15;                         // A/C col | B col
    const int q   = l >> 4;                         // quad (k-slice)
    const int ar  = n_ >> 2;                        // replicated A row -> batch row (0..3)
    const int rbase = blockIdx.x * 4;
    const int grow = q;                             // this lane's batch row (0..3)
    const int u    = qt * 16 + n_;                  // this lane's h unit 0..63
    const bool rd  = ((l & 3) == 0);                // cluster-reader lane

    // ---- LDS init: hbuf = 0 (h(-1)=0) ----
    for (int i = tid; i < 3 * 2 * 320; i += 768) (&hbuf[0][0][0])[i] = 0;

    // ---- stage all x for this WG's 4 rows (float4 loads -> bf16 LDS) ----
    {
        const float4* xv = (const float4*)(x + (size_t)rbase * (TT * 16));
        for (int i = tid; i < 8192; i += 768) {
            float4 v = xv[i];
            const int row = i >> 11, rem = i & 2047;    // 2048 float4 per row
            s16x4 pv = { f2bf(v.x), f2bf(v.y), f2bf(v.z), f2bf(v.w) };
            *(s16x4*)&xls[rem >> 2][row][(rem & 3) * 4] = pv;
        }
    }

    // ---- per-wave weight selection ----
    const float* Wih = (Ls == 0) ? Wih0 : (Ls == 1) ? Wih1 : Wih2;
    const float* Whh = (Ls == 0) ? Whh0 : (Ls == 1) ? Whh1 : Whh2;
    const float* bih = (Ls == 0) ? bih0 : (Ls == 1) ? bih1 : bih2;
    const float* bhh = (Ls == 0) ? bhh0 : (Ls == 1) ? bhh1 : bhh2;
    const int ldih = (Ls == 0) ? 16 : 64;   // W_ih0 is [192,16]; K zero-padded

    // gate scale folded into weights: r/z by -log2e (sigm via exp2),
    // n by 2*log2e (tanh via exp2)
    const float L2E = 1.44269504088896f;
    const float gsc0 = -L2E, gsc1 = -L2E, gsc2 = 2.0f * L2E;

    // ---- resident B-frags: gate g in {0=r,1=z,2=n}, cols g*64+qt*16.. ----
    // B-frag lane layout: col = n_, k = kt*32 + q*8 + j
    bf16x8 wihf[3][2], whhf[3][2];
#pragma unroll
    for (int g = 0; g < 3; ++g) {
        const int gc = g * 64 + qt * 16;
        const float sc = (g == 0) ? gsc0 : (g == 1) ? gsc1 : gsc2;
#pragma unroll
        for (int kt = 0; kt < 2; ++kt) {
            const int kb = kt * 32 + q * 8;
            bf16x8 fi, fh;
#pragma unroll
            for (int j = 0; j < 8; ++j) {
                const int k = kb + j;
                float vi = (k < ldih) ? Wih[(gc + n_) * ldih + k] : 0.0f;
                float vh = Whh[(gc + n_) * 64 + k];
                fi[j] = f2bf(vi * sc);
                fh[j] = f2bf(vh * sc);
            }
            wihf[g][kt] = fi;
            whhf[g][kt] = fh;
        }
    }

    // ---- loop-invariant bias fragments (seed MFMA C operand), gate-scaled ----
    const float br  = gsc0 * (bih[u] + bhh[u]);
    const float bz  = gsc1 * (bih[64 + u] + bhh[64 + u]);
    const float bxn = gsc2 * bih[128 + u];
    const float bhn = gsc2 * bhh[128 + u];
    const f32x4 fbr  = {br,  br,  br,  br};
    const f32x4 fbz  = {bz,  bz,  bz,  bz};
    const f32x4 fbxn = {bxn, bxn, bxn, bxn};
    const f32x4 fbhn = {bhn, bhn, bhn, bhn};
    const f32x4 zf4  = {0.f, 0.f, 0.f, 0.f};
    const bf16x8 zero8 = {0,0,0,0,0,0,0,0};

    // persistent masked-read tmps (inactive lanes keep stale/zero; never consumed)
    int4 th0 = {0,0,0,0}, th1 = {0,0,0,0};
    int4 ti0 = {0,0,0,0}, ti1 = {0,0,0,0};
    int4 tx0 = {0,0,0,0};

    float hp = 0.0f;   // this lane's h(row=grow, unit=u), carried fp32
    __syncthreads();

    // ---- pipelined time loop: wave of layer L processes t = s - L ----
    // Unrolled x2 so buffer parity is loop-invariant per copy.
#define GRU_STEP(sv, par)                                                          \
    {                                                                              \
        const int tw = (sv) - Ls;                                                  \
        if (tw >= 0 && tw < TT) {                                                  \
            const int bi = (par) ^ (Ls & 1);                                       \
            const short* own = &hbuf[Ls][bi ^ 1][0];                               \
            if (rd) {                                                              \
                th0 = *(const int4*)(own + ar * 80 + q * 8);                       \
                th1 = *(const int4*)(own + ar * 80 + 32 + q * 8);                  \
            }                                                                      \
            const bf16x8 hA0 = qbcast(th0);                                        \
            const bf16x8 hA1 = qbcast(th1);                                        \
            f32x4 ci_r, ci_z, ci_n;                                                \
            if (Ls == 0) {                                                         \
                bf16x8 xA0 = zero8;                                                \
                if (q < 2) {                                                       \
                    if (rd) tx0 = *(const int4*)(&xls[tw][ar][q * 8]);             \
                    xA0 = qbcast(tx0);                                             \
                }                                                                  \
                ci_r = MFMA16(xA0, wihf[0][0], fbr);                               \
                ci_z = MFMA16(xA0, wihf[1][0], fbz);                               \
                ci_n = MFMA16(xA0, wihf[2][0], fbxn);                              \
            } else {                                                               \
                const short* inp = &hbuf[Ls - 1][bi][0];                           \
                if (rd) {                                                          \
                    ti0 = *(const int4*)(inp + ar * 80 + q * 8);                   \
                    ti1 = *(const int4*)(inp + ar * 80 + 32 + q * 8);              \
                }                                                                  \
                const bf16x8 iA0 = qbcast(ti0);                                    \
                const bf16x8 iA1 = qbcast(ti1);                                    \
                ci_r = MFMA16(iA0, wihf[0][0], fbr);                               \
                ci_r = MFMA16(iA1, wihf[0][1], ci_r);                              \
                ci_z = MFMA16(iA0, wihf[1][0], fbz);                               \
                ci_z = MFMA16(iA1, wihf[1][1], ci_z);                              \
                ci_n = MFMA16(iA0, wihf[2][0], fbxn);                              \
                ci_n = MFMA16(iA1, wihf[2][1], ci_n);                              \
            }                                                                      \
            f32x4 ch_r = MFMA16(hA0, whhf[0][0], zf4);                             \
            ch_r = MFMA16(hA1, whhf[0][1], ch_r);                                  \
            f32x4 ch_z = MFMA16(hA0, whhf[1][0], zf4);                             \
            ch_z = MFMA16(hA1, whhf[1][1], ch_z);                                  \
            f32x4 ch_n = MFMA16(hA0, whhf[2][0], fbhn);                            \
            ch_n = MFMA16(hA1, whhf[2][1], ch_n);                                  \
            const float pr = ci_r[0] + ch_r[0];                                    \
            const float pz = ci_z[0] + ch_z[0];                                    \
            const float rr = __fdividef(1.0f, 1.0f + exp2f(pr));                   \
            const float zz = __fdividef(1.0f, 1.0f + exp2f(pz));                   \
            const float sn = ci_n[0] + rr * ch_n[0];                               \
            const float nn = 1.0f - __fdividef(2.0f, 1.0f + exp2f(sn));            \
            const float hv = nn + zz * (hp - nn);                                  \
            hp = hv;                                                               \
            hbuf[Ls][bi][grow * 80 + u] = f2bf(hv);                                \
        }                                                                          \
        __syncthreads();                                                           \
    }

    for (int s0 = 0; s0 < TT + 2; s0 += 2) {
        GRU_STEP(s0, 0)
        GRU_STEP(s0 + 1, 1)
    }
#undef GRU_STEP

    // ---- FC head: layer-2 waves hold h2(T-1), one value per lane ----
    if (wid >= 8) h2out[grow][u] = hp;
    __syncthreads();
    if (tid < 128) {
        const int row = tid >> 5, uu = tid & 31;
        float acc = fc1b[uu];
#pragma unroll
        for (int k = 0; k < 64; ++k) acc += h2out[row][k] * fc1w[uu * 64 + k];
        fcz[row][uu] = fmaxf(acc, 0.0f);
    }
    __syncthreads();
    if (tid < 4) {
        float y = fc2b[0];
#pragma unroll
        for (int uu = 0; uu < 32; ++uu) y += fcz[tid][uu] * fc2w[uu];
        out[rbase + tid] = y;
    }
}

extern "C" void kernel_launch(void* const* d_in, const int* in_sizes, int n_in,
                              void* d_out, int out_size, void* d_ws, size_t ws_size,
                              hipStream_t stream) {
    (void)in_sizes; (void)n_in; (void)d_ws; (void)ws_size; (void)out_size;
    gru_fused<<<dim3(256), dim3(768), 0, stream>>>(
        (const float*)d_in[0],
        (const float*)d_in[1],  (const float*)d_in[2],  (const float*)d_in[3],  (const float*)d_in[4],
        (const float*)d_in[5],  (const float*)d_in[6],  (const float*)d_in[7],  (const float*)d_in[8],
        (const float*)d_in[9],  (const float*)d_in[10], (const float*)d_in[11], (const float*)d_in[12],
        (const float*)d_in[13], (const float*)d_in[14], (const float*)d_in[15], (const float*)d_in[16],
        (float*)d_out);
}